// Round 19
// baseline (163.424 us; speedup 1.0000x reference)
//
#include <hip/hip_runtime.h>
#include <stdint.h>

#define S_LEN 2048
#define DMODEL 2048
#define NH 32
#define NKV 8
#define HD 64

typedef __attribute__((ext_vector_type(8))) __bf16 bf16x8;
typedef __attribute__((ext_vector_type(4))) float f32x4;
typedef __attribute__((ext_vector_type(16))) float f32x16;

__device__ __forceinline__ unsigned short f2bf(float f) {
    union { float f; uint32_t u; } v; v.f = f;
    uint32_t u = v.u;
    u += 0x7FFFu + ((u >> 16) & 1u);
    return (unsigned short)(u >> 16);
}

__device__ __forceinline__ uint32_t cvt_pk_bf16(float lo, float hi) {
    uint32_t r;
    asm("v_cvt_pk_bf16_f32 %0, %1, %2" : "=v"(r) : "v"(lo), "v"(hi));
    return r;
}

#define GLDS16(g, l)                                                          \
    __builtin_amdgcn_global_load_lds(                                         \
        (const __attribute__((address_space(1))) unsigned int*)(g),           \
        (__attribute__((address_space(3))) unsigned int*)(l), 16, 0, 0)

// 40 units/head (R13-verified): chunks of <=16 KVBLK-32 tiles, longest-first.
__device__ const int8_t kUQT[40] = {3,4,5,6,7,7,8,8,9,9,10,10,11,11,11,12,12,12,13,13,13,14,14,14,15,15,15,15,
                                    2,6,10,14, 1,5,9,13, 0,4,8,12};
__device__ const int8_t kUCH[40] = {0,0,0,0,0,1,0,1,0,1,0,1,0,1,2,0,1,2,0,1,2,0,1,2,0,1,2,3,
                                    0,1,2,3, 0,1,2,3, 0,1,2,3};

__device__ __forceinline__ int slot_base(int qt) {  // strips qt>=4 only
    return (qt < 8) ? (qt - 4) * 2 : (qt < 12) ? 8 + (qt - 8) * 3
                                               : 20 + (qt - 12) * 4;
}

// ------- merged prep: z<5 weight transposes, z=5 x cast ------------------
__global__ void prep_kernel(
    const float* __restrict__ wq, const float* __restrict__ wk,
    const float* __restrict__ wv, const float* __restrict__ wo,
    const float* __restrict__ fw, const float* __restrict__ x,
    unsigned short* __restrict__ wqkvT, unsigned short* __restrict__ woT,
    unsigned short* __restrict__ fwT, unsigned short* __restrict__ xb) {
    const int z = blockIdx.z;
    const int tx = threadIdx.x, ty = threadIdx.y;
    if (z == 5) {  // cast x -> bf16
        int base = (blockIdx.y * 64 + blockIdx.x) * 1024 + (ty * 32 + tx) * 4;
        float4 a = *(const float4*)&x[base];
        ushort4 o;
        o.x = f2bf(a.x); o.y = f2bf(a.y); o.z = f2bf(a.z); o.w = f2bf(a.w);
        *(ushort4*)&xb[base] = o;
        return;
    }
    __shared__ float tile[32][33];
    const float* src;
    unsigned short* dst;
    int R, C;
    if (z == 0)      { src = wq; dst = wqkvT;                       R = 2048; C = 2048; }
    else if (z == 1) { src = wk; dst = wqkvT + (size_t)2048 * 2048; R = 2048; C = 512;  if (blockIdx.x >= 16) return; }
    else if (z == 2) { src = wv; dst = wqkvT + (size_t)2560 * 2048; R = 2048; C = 512;  if (blockIdx.x >= 16) return; }
    else if (z == 3) { src = wo; dst = woT;                         R = 2048; C = 2048; }
    else             { src = fw; dst = fwT;                         R = 64;   C = 64;   if (blockIdx.x >= 2 || blockIdx.y >= 2) return; }
    int c0 = blockIdx.x * 32, r0 = blockIdx.y * 32;
#pragma unroll
    for (int i = 0; i < 32; i += 8)
        tile[ty + i][tx] = src[(size_t)(r0 + ty + i) * C + c0 + tx];
    __syncthreads();
#pragma unroll
    for (int i = 0; i < 32; i += 8)
        dst[(size_t)(c0 + ty + i) * R + r0 + tx] = f2bf(tile[tx][ty + i]);
}

// ---- 128x64-tile triple-buffered counted-vmcnt bf16 GEMM (R14 version) ----
// MODE 0: fp32 out (wo).  MODE 1: fused QKV epilogue -> Qb/Kb/VT.
template <int MODE>
__global__ __launch_bounds__(256) void gemm_bt_kernel(
    const unsigned short* __restrict__ A, const unsigned short* __restrict__ BT,
    float* __restrict__ C0, unsigned short* __restrict__ Qb,
    unsigned short* __restrict__ Kb, unsigned short* __restrict__ VT,
    const float* __restrict__ fcos, const float* __restrict__ fsin,
    int M, int N, int K) {
    __shared__ unsigned short As[3][128 * 32];
    __shared__ unsigned short Bs[3][64 * 32];
    const int t = threadIdx.x;
    const int lane = t & 63, wave = t >> 6;
    const int wr = wave >> 1, wc = wave & 1;
    const int gx = gridDim.x;
    const int nwg = gx * gridDim.y;
    const int wg = blockIdx.y * gx + blockIdx.x;
    const int swz = (wg & 7) * (nwg >> 3) + (wg >> 3);
    const int m0 = (swz % gx) * 128, n0 = (swz / gx) * 64;
    const int l15 = lane & 15, lhi = lane >> 4;
    f32x4 acc[4][2] = {};
    const unsigned short* ga = A + (size_t)(m0 + (t >> 2)) * K + (t & 3) * 8;
    const unsigned short* gb = BT + (size_t)(n0 + (t >> 2)) * K + (t & 3) * 8;
    const int nk = K >> 5;

#define GSTAGE(buf, kt)                                                       \
    {                                                                         \
        const int k0_ = (kt) * 32;                                            \
        GLDS16(ga + k0_, &As[buf][t * 8]);                                    \
        GLDS16(ga + (size_t)64 * K + k0_, &As[buf][t * 8 + 64 * 32]);         \
        if (t < 256) GLDS16(gb + k0_, &Bs[buf][t * 8]);                       \
    }

    GSTAGE(0, 0);
    GSTAGE(1, 1);

    int cb = 0, pfb = 2;
#pragma unroll 1
    for (int kt = 0; kt < nk; ++kt) {
        if (kt + 1 < nk) asm volatile("s_waitcnt vmcnt(3)" ::: "memory");
        else             asm volatile("s_waitcnt vmcnt(0)" ::: "memory");
        __builtin_amdgcn_s_barrier();
        __builtin_amdgcn_sched_barrier(0);
        if (kt + 2 < nk) GSTAGE(pfb, kt + 2);
        pfb = (pfb == 2) ? 0 : pfb + 1;
        const int mycb = cb;
        cb = (cb == 2) ? 0 : cb + 1;
        bf16x8 af[4], bfr[2];
#pragma unroll
        for (int m = 0; m < 4; m++)
            af[m] = *(const bf16x8*)&As[mycb][(wr * 64 + m * 16 + l15) * 32 + lhi * 8];
#pragma unroll
        for (int n = 0; n < 2; n++)
            bfr[n] = *(const bf16x8*)&Bs[mycb][(wc * 32 + n * 16 + l15) * 32 + lhi * 8];
#pragma unroll
        for (int m = 0; m < 4; m++)
#pragma unroll
            for (int n = 0; n < 2; n++)
                acc[m][n] = __builtin_amdgcn_mfma_f32_16x16x32_bf16(
                    af[m], bfr[n], acc[m][n], 0, 0, 0);
    }
#undef GSTAGE
    if (MODE == 0) {
#pragma unroll
        for (int m = 0; m < 4; m++) {
            int row = m0 + wr * 64 + m * 16 + lhi * 4;
#pragma unroll
            for (int n = 0; n < 2; n++) {
                int col = n0 + wc * 32 + n * 16 + l15;
#pragma unroll
                for (int r = 0; r < 4; r++)
                    C0[(size_t)(row + r) * N + col] = acc[m][n][r];
            }
        }
    } else {
        const int nblk = n0 >> 6;  // 0..47: Q heads 0..31, K 32..39, V 40..47
        if (nblk < 40) {
            const float CS = 0.125f * 1.44269504f;
            const bool isQ = (nblk < 32);
            unsigned short* dst = isQ ? Qb + (size_t)nblk * (S_LEN * HD)
                                      : Kb + (size_t)(nblk - 32) * (S_LEN * HD);
#pragma unroll
            for (int m = 0; m < 4; m++) {
#pragma unroll
                for (int n = 0; n < 2; n++) {
                    int col = wc * 32 + n * 16 + l15;  // head-local d
                    int i = col >> 1;
                    float sgn = (col & 1) ? 1.f : -1.f;
#pragma unroll
                    for (int r = 0; r < 4; r++) {
                        int s = m0 + wr * 64 + m * 16 + lhi * 4 + r;
                        float c = fcos[s * 32 + i], sn = fsin[s * 32 + i];
                        float v = acc[m][n][r];
                        float pv = __shfl_xor(v, 1);
                        float o = fmaf(pv, sgn * sn, v * c);
                        if (isQ) o *= CS;
                        dst[(size_t)s * HD + col] = f2bf(o);
                    }
                }
            }
        } else {
            // V path: LDS transpose [64 d][128 s] (pad 130), coalesced out
            const int kvh = nblk - 40;
            unsigned short* ldsT = (unsigned short*)As;
            __syncthreads();
#pragma unroll
            for (int m = 0; m < 4; m++)
#pragma unroll
                for (int n = 0; n < 2; n++) {
                    int d = wc * 32 + n * 16 + l15;
#pragma unroll
                    for (int r = 0; r < 4; r++) {
                        int sl = wr * 64 + m * 16 + lhi * 4 + r;
                        ldsT[d * 130 + sl] = f2bf(acc[m][n][r]);
                    }
                }
            __syncthreads();
            const int d = t >> 2, sc = (t & 3) * 32;
            unsigned short* dst = VT + ((size_t)kvh * HD + d) * S_LEN + m0 + sc;
            const unsigned short* srcl = &ldsT[d * 130 + sc];
#pragma unroll
            for (int j = 0; j < 16; j++)
                ((uint32_t*)dst)[j] = *(const uint32_t*)&srcl[2 * j];
        }
    }
}

// ---------------- flash attention v11: KVBLK=32, 40 units/head -------------
// 1280 blocks x 256 threads (4 waves), 24KB LDS -> 5 blocks/CU ALL resident.
// Unit u of head h: chunk ch (<=16 tiles) of strip qt. Per-tile math = R17.
// Strips qt>=4 write fp32 partials (nc=2..4); fw_silu merges inline.
__global__ __launch_bounds__(256) void flash_kernel(
    const unsigned short* __restrict__ Q, const unsigned short* __restrict__ Kg,
    const unsigned short* __restrict__ VTg, unsigned short* __restrict__ O,
    float* __restrict__ Opart, float* __restrict__ ML) {
    __shared__ unsigned short Ks[3][2048];
    __shared__ unsigned short Vs[3][2048];
    const int t = threadIdx.x, lane = t & 63, wave = t >> 6;
    const int l31 = lane & 31, hi = lane >> 5;
    const int bid = blockIdx.x;
    const int h = bid & 31, u = bid >> 5;  // u 0..39
    const int qt = kUQT[u], ch = kUCH[u];
    const int sp = (qt >= 4);
    const int kvh = h >> 2;

    const int kt0 = ch * 16;
    const int ktN = min(kt0 + 16, 4 * qt + 4);

    const int srow = t >> 3;
    const int scol = ((t & 7) * 8) ^ ((srow & 7) * 8);
    const unsigned short* gk = Kg + ((size_t)kvh * S_LEN + srow) * HD + scol;
    const int vrow = t >> 2;
    const int vcol = (((t & 3) ^ (vrow & 3)) * 8);
    const unsigned short* gv = VTg + ((size_t)kvh * HD + vrow) * S_LEN + vcol;

    const int q0 = qt * 128;
    const int qw0 = q0 + wave * 32;  // wave's first q row
    const int q = qw0 + l31;         // THIS lane's q row

    const unsigned short* qp = Q + ((size_t)h * S_LEN + q) * HD + hi * 8;
    bf16x8 qf0 = *(const bf16x8*)(qp);
    bf16x8 qf1 = *(const bf16x8*)(qp + 16);
    bf16x8 qf2 = *(const bf16x8*)(qp + 32);
    bf16x8 qf3 = *(const bf16x8*)(qp + 48);

    f32x16 oacc0 = {}, oacc1 = {};  // O^T: col q, rows d (0..31 / 32..63)
    float mrun = -1e30f, lrun = 0.f;

#define FSTAGE(buf, kt)                                                       \
    {                                                                         \
        const size_t kv_ = (size_t)(kt) * 32;                                 \
        GLDS16(gk + kv_ * HD, &Ks[buf][t * 8]);                               \
        GLDS16(gv + kv_, &Vs[buf][t * 8]);                                    \
    }

    FSTAGE(0, kt0);
    FSTAGE(1, kt0 + 1);

    int cb = 0, pfb = 2;
#pragma unroll 1
    for (int kt = kt0; kt < ktN; ++kt) {
        if (kt + 1 < ktN) asm volatile("s_waitcnt vmcnt(2)" ::: "memory");
        else              asm volatile("s_waitcnt vmcnt(0)" ::: "memory");
        __builtin_amdgcn_s_barrier();
        __builtin_amdgcn_sched_barrier(0);
        if (kt + 2 < ktN) FSTAGE(pfb, kt + 2);
        pfb = (pfb == 2) ? 0 : pfb + 1;
        const int kv0 = kt * 32;
        const int mycb = cb;
        cb = (cb == 2) ? 0 : cb + 1;
        if (kv0 > qw0 + 31) continue;  // fully-masked for this wave
        const unsigned short* ksb = Ks[mycb];
        const unsigned short* vsb = Vs[mycb];
        const int sw = (l31 & 7) * 8;
        // S^T = K Q^T (32 kv x 32 q)
        f32x16 s0 = {};
#pragma unroll
        for (int kc = 0; kc < 4; kc++) {
            bf16x8 k0 = *(const bf16x8*)&ksb[l31 * 64 + ((16 * kc + 8 * hi) ^ sw)];
            bf16x8 qc = (kc == 0) ? qf0 : (kc == 1) ? qf1 : (kc == 2) ? qf2 : qf3;
            s0 = __builtin_amdgcn_mfma_f32_32x32x16_bf16(k0, qc, s0, 0, 0, 0);
        }
        float p0[16];
        if (kv0 + 31 <= qw0) {  // interior tile
#pragma unroll
            for (int r = 0; r < 16; r++) p0[r] = s0[r];
        } else {
#pragma unroll
            for (int r = 0; r < 16; r++) {
                int rr = (r & 3) + 8 * (r >> 2) + 4 * hi;
                p0[r] = (kv0 + rr <= q) ? s0[r] : -1e30f;
            }
        }
        float t8[8];
#pragma unroll
        for (int r = 0; r < 8; r++) t8[r] = fmaxf(p0[r], p0[r + 8]);
        float lm = fmaxf(fmaxf(fmaxf(t8[0], t8[4]), fmaxf(t8[1], t8[5])),
                         fmaxf(fmaxf(t8[2], t8[6]), fmaxf(t8[3], t8[7])));
        if (!__all(lm - mrun <= 8.f)) {
            float rm = fmaxf(lm, __shfl_xor(lm, 32));
            float mnew = fmaxf(mrun, rm);
            float sc = exp2f(mrun - mnew);
            mrun = mnew;
            lrun *= sc;
            oacc0 *= sc;
            oacc1 *= sc;
        }
#pragma unroll
        for (int r = 0; r < 16; r++) p0[r] = exp2f(p0[r] - mrun);
        float sA = 0.f, sB = 0.f;
#pragma unroll
        for (int r = 0; r < 4; r++) {
            sA += p0[r] + p0[r + 4];
            sB += p0[r + 8] + p0[r + 12];
        }
        lrun += sA + sB;
        bf16x8 pf[2];
#pragma unroll
        for (int kc = 0; kc < 2; kc++) {
            const int sub = kc * 8;
            uint32_t Wl0 = cvt_pk_bf16(p0[sub + 0], p0[sub + 1]);
            uint32_t Wl1 = cvt_pk_bf16(p0[sub + 2], p0[sub + 3]);
            uint32_t Wh0 = cvt_pk_bf16(p0[sub + 4], p0[sub + 5]);
            uint32_t Wh1 = cvt_pk_bf16(p0[sub + 6], p0[sub + 7]);
            uint32_t sw0 = hi ? Wl0 : Wh0, sw1 = hi ? Wl1 : Wh1;  // sent
            uint32_t rc0 = __shfl_xor((int)sw0, 32);
            uint32_t rc1 = __shfl_xor((int)sw1, 32);
            uint32_t kp0 = hi ? Wh0 : Wl0, kp1 = hi ? Wh1 : Wl1;  // kept
            uint32_t F0 = hi ? rc0 : kp0;
            uint32_t F1 = hi ? rc1 : kp1;
            uint32_t F2 = hi ? kp0 : rc0;
            uint32_t F3 = hi ? kp1 : rc1;
            uint4 fu = {F0, F1, F2, F3};
            pf[kc] = *(const bf16x8*)&fu;
        }
#pragma unroll
        for (int kc = 0; kc < 2; kc++) {
            const int vs0 = ((kc * 2 + hi) ^ (l31 & 3)) * 8;
            bf16x8 v0 = *(const bf16x8*)&vsb[l31 * 32 + vs0];
            bf16x8 v1 = *(const bf16x8*)&vsb[(32 + l31) * 32 + vs0];
            oacc0 = __builtin_amdgcn_mfma_f32_32x32x16_bf16(v0, pf[kc], oacc0, 0, 0, 0);
            oacc1 = __builtin_amdgcn_mfma_f32_32x32x16_bf16(v1, pf[kc], oacc1, 0, 0, 0);
        }
    }
#undef FSTAGE
    lrun += __shfl_xor(lrun, 32);
    const int qrow = wave * 32 + l31;
    if (sp) {
        const int slot = h * 36 + slot_base(qt) + ch;
        float* po = Opart + ((size_t)slot * 128 + qrow) * 64 + 4 * hi;
#pragma unroll
        for (int g = 0; g < 4; g++) {
            float4 a = {oacc0[4 * g], oacc0[4 * g + 1], oacc0[4 * g + 2], oacc0[4 * g + 3]};
            *(float4*)(po + 8 * g) = a;
            float4 b = {oacc1[4 * g], oacc1[4 * g + 1], oacc1[4 * g + 2], oacc1[4 * g + 3]};
            *(float4*)(po + 32 + 8 * g) = b;
        }
        if (hi == 0) {
            ML[((size_t)slot * 128 + qrow) * 2] = mrun;
            ML[((size_t)slot * 128 + qrow) * 2 + 1] = lrun;
        }
    } else {
        float rinv = 1.f / lrun;
        unsigned short* ob = O + ((size_t)h * S_LEN + q) * HD + 4 * hi;
#pragma unroll
        for (int g = 0; g < 4; g++) {
            uint32_t a0 = cvt_pk_bf16(oacc0[4 * g] * rinv, oacc0[4 * g + 1] * rinv);
            uint32_t a1 = cvt_pk_bf16(oacc0[4 * g + 2] * rinv, oacc0[4 * g + 3] * rinv);
            uint2 u0 = {a0, a1};
            *(uint2*)(ob + 8 * g) = u0;
            uint32_t b0 = cvt_pk_bf16(oacc1[4 * g] * rinv, oacc1[4 * g + 1] * rinv);
            uint32_t b1 = cvt_pk_bf16(oacc1[4 * g + 2] * rinv, oacc1[4 * g + 3] * rinv);
            uint2 u1 = {b0, b1};
            *(uint2*)(ob + 32 + 8 * g) = u1;
        }
    }
}

// ---- per-head fw GEMM + SiLU, fused nc-way partial combine ----------------
// Rows s<512 read bf16 attn; rows s>=512 merge nc=2..4 kv-chunk fp32
// partials inline (branches wave-uniform: 16 rows/wave share one strip).
__global__ __launch_bounds__(256) void fw_silu_kernel(
    const unsigned short* __restrict__ AT, const unsigned short* __restrict__ fwT,
    const float* __restrict__ fb, const float* __restrict__ Opart,
    const float* __restrict__ ML, unsigned short* __restrict__ h2) {
    const int t = threadIdx.x, lane = t & 63, wave = t >> 6;
    const int l15 = lane & 15, lhi = lane >> 4;
    const int r0 = blockIdx.x * 64 + wave * 16;
    const int row = r0 + l15;
    const int hh = row >> 11, s = row & (S_LEN - 1);
    bf16x8 a0, a1;
    if (s < 512) {
        const unsigned short* ap = AT + (size_t)row * HD + lhi * 8;
        a0 = *(const bf16x8*)ap;
        a1 = *(const bf16x8*)(ap + 32);
    } else {
        const int qt = s >> 7, qrow = s & 127;
        const int nc = (qt < 8) ? 2 : (qt < 12) ? 3 : 4;
        const int slot0 = hh * 36 + slot_base(qt);
        float mc[4], lc[4];
#pragma unroll
        for (int c = 0; c < 4; c++) {
            if (c < nc) {
                const float* p = ML + ((size_t)(slot0 + c) * 128 + qrow) * 2;
                mc[c] = p[0]; lc[c] = p[1];
            } else { mc[c] = -1e30f; lc[c] = 0.f; }
        }
        float mm = fmaxf(fmaxf(mc[0], mc[1]), fmaxf(mc[2], mc[3]));
        float wgt[4]; float den = 0.f;
#pragma unroll
        for (int c = 0; c < 4; c++) {
            wgt[c] = exp2f(mc[c] - mm);
            den += lc[c] * wgt[c];
        }
        float rv = 1.f / den;
#pragma unroll
        for (int half = 0; half < 2; half++) {
            int db = half * 32 + lhi * 8;
            float acc8[8] = {};
#pragma unroll
            for (int c = 0; c < 4; c++) {
                if (c < nc) {
                    const float* pc = Opart + ((size_t)(slot0 + c) * 128 + qrow) * 64 + db;
                    float4 x0 = *(const float4*)pc, x1 = *(const float4*)(pc + 4);
                    acc8[0] += x0.x * wgt[c]; acc8[1] += x0.y * wgt[c];
                    acc8[2] += x0.z * wgt[c]; acc8[3] += x0.w * wgt[c];
                    acc8[4] += x1.x * wgt[c]; acc8[5] += x1.y * wgt[c];
                    acc8[6] += x1.z * wgt[c]; acc8[7] += x1.w * wgt[c];
                }
            }
            uint32_t w0 = cvt_pk_bf16(acc8[0] * rv, acc8[1] * rv);
            uint32_t w1 = cvt_pk_bf16(acc8[2] * rv, acc8[3] * rv);
            uint32_t w2 = cvt_pk_bf16(acc8[4] * rv, acc8[5] * rv);
            uint32_t w3 = cvt_pk_bf16(acc8[6] * rv, acc8[7] * rv);
            uint4 u = {w0, w1, w2, w3};
            if (half == 0) a0 = *(const bf16x8*)&u;
            else           a1 = *(const bf16x8*)&u;
        }
    }
    f32x4 acc[4] = {};
#pragma unroll
    for (int nb = 0; nb < 4; nb++) {
        const unsigned short* bp = fwT + (size_t)(nb * 16 + l15) * HD + lhi * 8;
        bf16x8 b0 = *(const bf16x8*)bp;
        bf16x8 b1 = *(const bf16x8*)(bp + 32);
        acc[nb] = __builtin_amdgcn_mfma_f32_16x16x32_bf16(a0, b0, acc[nb], 0, 0, 0);
        acc[nb] = __builtin_amdgcn_mfma_f32_16x16x32_bf16(a1, b1, acc[nb], 0, 0, 0);
    }
#pragma unroll
    for (int nb = 0; nb < 4; nb++) {
        int col = nb * 16 + l15;
        float bias = fb[col];
#pragma unroll
        for (int r = 0; r < 4; r++) {
            int orow = r0 + lhi * 4 + r;  // h*S + s
            int os = orow & (S_LEN - 1), oh = orow >> 11;
            float xv = acc[nb][r] + bias;
            float sg = 1.f / (1.f + exp2f(-xv * 1.44269504f));
            h2[(size_t)os * DMODEL + oh * HD + col] = f2bf(xv * sg);
        }
    }
}

extern "C" void kernel_launch(void* const* d_in, const int* in_sizes, int n_in,
                              void* d_out, int out_size, void* d_ws, size_t ws_size,
                              hipStream_t stream) {
    const float* x = (const float*)d_in[0];
    const float* fcos = (const float*)d_in[1];
    const float* fsin = (const float*)d_in[2];
    const float* wq = (const float*)d_in[4];
    const float* wk = (const float*)d_in[5];
    const float* wv = (const float*)d_in[6];
    const float* wo = (const float*)d_in[7];
    const float* fw = (const float*)d_in[8];
    const float* fb = (const float*)d_in[9];
    float* out = (float*)d_out;

    char* ws = (char*)d_ws;
    size_t off = 0;
    auto alloc = [&](size_t bytes) {
        void* p = ws + off;
        off += (bytes + 255) & ~(size_t)255;
        return p;
    };
    unsigned short* wqkvT = (unsigned short*)alloc((size_t)3072 * 2048 * 2);
    unsigned short* woT   = (unsigned short*)alloc((size_t)2048 * 2048 * 2);
    unsigned short* fwT   = (unsigned short*)alloc((size_t)64 * 64 * 2);
    unsigned short* Qb    = (unsigned short*)alloc((size_t)NH * S_LEN * HD * 2);
    unsigned short* Kb    = (unsigned short*)alloc((size_t)NKV * S_LEN * HD * 2);
    unsigned short* VT    = (unsigned short*)alloc((size_t)NKV * HD * S_LEN * 2);
    unsigned short* xb    = (unsigned short*)alloc((size_t)2048 * 2048 * 2);
    float*          ML    = (float*)alloc((size_t)1152 * 128 * 2 * 4);
    unsigned short* attn  = (unsigned short*)alloc((size_t)NH * S_LEN * HD * 2);
    float*          Opart = (float*)alloc((size_t)1152 * 128 * 64 * 4);
    unsigned short* h2 = xb;  // reuses xb (x dead after QKV gemm)

    prep_kernel<<<dim3(64, 64, 6), dim3(32, 8), 0, stream>>>(
        wq, wk, wv, wo, fw, x, wqkvT, woT, fwT, xb);

    // QKV GEMM (128x64, BK=32) w/ fused RoPE/V-transpose epilogue
    gemm_bt_kernel<1><<<dim3(16, 48), 256, 0, stream>>>(
        xb, wqkvT, nullptr, Qb, Kb, VT, fcos, fsin, 2048, 3072, 2048);

    flash_kernel<<<1280, 256, 0, stream>>>(Qb, Kb, VT, attn, Opart, ML);

    // fw GEMM + SiLU with fused nc-way partial combine
    fw_silu_kernel<<<1024, 256, 0, stream>>>(attn, fwT, fb, Opart, ML, h2);

    // wo GEMM: 128x64, BK=32, fp32 out
    gemm_bt_kernel<0><<<dim3(16, 32), 256, 0, stream>>>(
        h2, woT, out, nullptr, nullptr, nullptr, nullptr, nullptr,
        2048, 2048, 2048);
}

// Round 20
// 155.905 us; speedup vs baseline: 1.0482x; 1.0482x over previous
//
#include <hip/hip_runtime.h>
#include <stdint.h>

#define S_LEN 2048
#define DMODEL 2048
#define NH 32
#define NKV 8
#define HD 64

typedef __attribute__((ext_vector_type(8))) __bf16 bf16x8;
typedef __attribute__((ext_vector_type(4))) float f32x4;
typedef __attribute__((ext_vector_type(16))) float f32x16;

__device__ __forceinline__ unsigned short f2bf(float f) {
    union { float f; uint32_t u; } v; v.f = f;
    uint32_t u = v.u;
    u += 0x7FFFu + ((u >> 16) & 1u);
    return (unsigned short)(u >> 16);
}

__device__ __forceinline__ uint32_t cvt_pk_bf16(float lo, float hi) {
    uint32_t r;
    asm("v_cvt_pk_bf16_f32 %0, %1, %2" : "=v"(r) : "v"(lo), "v"(hi));
    return r;
}

#define GLDS16(g, l)                                                          \
    __builtin_amdgcn_global_load_lds(                                         \
        (const __attribute__((address_space(1))) unsigned int*)(g),           \
        (__attribute__((address_space(3))) unsigned int*)(l), 16, 0, 0)

// unit tables (R12): 24 units/head, sorted descending by length.
__device__ const int kUQT[24] = {15,15,7,14,14,13,13,6,12,12,11,11,5,10,10,9,9,4,8,8,3,2,1,0};
__device__ const int kUCH[24] = {0,1,0,0,1,0,1,0,0,1,0,1,0,0,1,0,1,0,0,1,0,0,0,0};
__device__ const int kUSP[24] = {1,1,0,1,1,1,1,0,1,1,1,1,0,1,1,1,1,0,1,1,0,0,0,0};

// ------- merged prep: z<5 weight transposes, z=5 x cast ------------------
__global__ void prep_kernel(
    const float* __restrict__ wq, const float* __restrict__ wk,
    const float* __restrict__ wv, const float* __restrict__ wo,
    const float* __restrict__ fw, const float* __restrict__ x,
    unsigned short* __restrict__ wqkvT, unsigned short* __restrict__ woT,
    unsigned short* __restrict__ fwT, unsigned short* __restrict__ xb) {
    const int z = blockIdx.z;
    const int tx = threadIdx.x, ty = threadIdx.y;
    if (z == 5) {  // cast x -> bf16
        int base = (blockIdx.y * 64 + blockIdx.x) * 1024 + (ty * 32 + tx) * 4;
        float4 a = *(const float4*)&x[base];
        ushort4 o;
        o.x = f2bf(a.x); o.y = f2bf(a.y); o.z = f2bf(a.z); o.w = f2bf(a.w);
        *(ushort4*)&xb[base] = o;
        return;
    }
    __shared__ float tile[32][33];
    const float* src;
    unsigned short* dst;
    int R, C;
    if (z == 0)      { src = wq; dst = wqkvT;                       R = 2048; C = 2048; }
    else if (z == 1) { src = wk; dst = wqkvT + (size_t)2048 * 2048; R = 2048; C = 512;  if (blockIdx.x >= 16) return; }
    else if (z == 2) { src = wv; dst = wqkvT + (size_t)2560 * 2048; R = 2048; C = 512;  if (blockIdx.x >= 16) return; }
    else if (z == 3) { src = wo; dst = woT;                         R = 2048; C = 2048; }
    else             { src = fw; dst = fwT;                         R = 64;   C = 64;   if (blockIdx.x >= 2 || blockIdx.y >= 2) return; }
    int c0 = blockIdx.x * 32, r0 = blockIdx.y * 32;
#pragma unroll
    for (int i = 0; i < 32; i += 8)
        tile[ty + i][tx] = src[(size_t)(r0 + ty + i) * C + c0 + tx];
    __syncthreads();
#pragma unroll
    for (int i = 0; i < 32; i += 8)
        dst[(size_t)(c0 + ty + i) * R + r0 + tx] = f2bf(tile[tx][ty + i]);
}

// ---- 128x64-tile triple-buffered counted-vmcnt bf16 GEMM (R14 version) ----
// MODE 0: fp32 out (wo).  MODE 1: fused QKV epilogue -> Qb/Kb/VT.
template <int MODE>
__global__ __launch_bounds__(256) void gemm_bt_kernel(
    const unsigned short* __restrict__ A, const unsigned short* __restrict__ BT,
    float* __restrict__ C0, unsigned short* __restrict__ Qb,
    unsigned short* __restrict__ Kb, unsigned short* __restrict__ VT,
    const float* __restrict__ fcos, const float* __restrict__ fsin,
    int M, int N, int K) {
    __shared__ unsigned short As[3][128 * 32];
    __shared__ unsigned short Bs[3][64 * 32];
    const int t = threadIdx.x;
    const int lane = t & 63, wave = t >> 6;
    const int wr = wave >> 1, wc = wave & 1;
    const int gx = gridDim.x;
    const int nwg = gx * gridDim.y;
    const int wg = blockIdx.y * gx + blockIdx.x;
    const int swz = (wg & 7) * (nwg >> 3) + (wg >> 3);
    const int m0 = (swz % gx) * 128, n0 = (swz / gx) * 64;
    const int l15 = lane & 15, lhi = lane >> 4;
    f32x4 acc[4][2] = {};
    const unsigned short* ga = A + (size_t)(m0 + (t >> 2)) * K + (t & 3) * 8;
    const unsigned short* gb = BT + (size_t)(n0 + (t >> 2)) * K + (t & 3) * 8;
    const int nk = K >> 5;

#define GSTAGE(buf, kt)                                                       \
    {                                                                         \
        const int k0_ = (kt) * 32;                                            \
        GLDS16(ga + k0_, &As[buf][t * 8]);                                    \
        GLDS16(ga + (size_t)64 * K + k0_, &As[buf][t * 8 + 64 * 32]);         \
        if (t < 256) GLDS16(gb + k0_, &Bs[buf][t * 8]);                       \
    }

    GSTAGE(0, 0);
    GSTAGE(1, 1);

    int cb = 0, pfb = 2;
#pragma unroll 1
    for (int kt = 0; kt < nk; ++kt) {
        if (kt + 1 < nk) asm volatile("s_waitcnt vmcnt(3)" ::: "memory");
        else             asm volatile("s_waitcnt vmcnt(0)" ::: "memory");
        __builtin_amdgcn_s_barrier();
        __builtin_amdgcn_sched_barrier(0);
        if (kt + 2 < nk) GSTAGE(pfb, kt + 2);
        pfb = (pfb == 2) ? 0 : pfb + 1;
        const int mycb = cb;
        cb = (cb == 2) ? 0 : cb + 1;
        bf16x8 af[4], bfr[2];
#pragma unroll
        for (int m = 0; m < 4; m++)
            af[m] = *(const bf16x8*)&As[mycb][(wr * 64 + m * 16 + l15) * 32 + lhi * 8];
#pragma unroll
        for (int n = 0; n < 2; n++)
            bfr[n] = *(const bf16x8*)&Bs[mycb][(wc * 32 + n * 16 + l15) * 32 + lhi * 8];
#pragma unroll
        for (int m = 0; m < 4; m++)
#pragma unroll
            for (int n = 0; n < 2; n++)
                acc[m][n] = __builtin_amdgcn_mfma_f32_16x16x32_bf16(
                    af[m], bfr[n], acc[m][n], 0, 0, 0);
    }
#undef GSTAGE
    if (MODE == 0) {
#pragma unroll
        for (int m = 0; m < 4; m++) {
            int row = m0 + wr * 64 + m * 16 + lhi * 4;
#pragma unroll
            for (int n = 0; n < 2; n++) {
                int col = n0 + wc * 32 + n * 16 + l15;
#pragma unroll
                for (int r = 0; r < 4; r++)
                    C0[(size_t)(row + r) * N + col] = acc[m][n][r];
            }
        }
    } else {
        const int nblk = n0 >> 6;  // 0..47: Q heads 0..31, K 32..39, V 40..47
        if (nblk < 40) {
            const float CS = 0.125f * 1.44269504f;
            const bool isQ = (nblk < 32);
            unsigned short* dst = isQ ? Qb + (size_t)nblk * (S_LEN * HD)
                                      : Kb + (size_t)(nblk - 32) * (S_LEN * HD);
#pragma unroll
            for (int m = 0; m < 4; m++) {
#pragma unroll
                for (int n = 0; n < 2; n++) {
                    int col = wc * 32 + n * 16 + l15;  // head-local d
                    int i = col >> 1;
                    float sgn = (col & 1) ? 1.f : -1.f;
#pragma unroll
                    for (int r = 0; r < 4; r++) {
                        int s = m0 + wr * 64 + m * 16 + lhi * 4 + r;
                        float c = fcos[s * 32 + i], sn = fsin[s * 32 + i];
                        float v = acc[m][n][r];
                        float pv = __shfl_xor(v, 1);
                        float o = fmaf(pv, sgn * sn, v * c);
                        if (isQ) o *= CS;
                        dst[(size_t)s * HD + col] = f2bf(o);
                    }
                }
            }
        } else {
            // V path: LDS transpose [64 d][128 s] (pad 130), coalesced out
            const int kvh = nblk - 40;
            unsigned short* ldsT = (unsigned short*)As;
            __syncthreads();
#pragma unroll
            for (int m = 0; m < 4; m++)
#pragma unroll
                for (int n = 0; n < 2; n++) {
                    int d = wc * 32 + n * 16 + l15;
#pragma unroll
                    for (int r = 0; r < 4; r++) {
                        int sl = wr * 64 + m * 16 + lhi * 4 + r;
                        ldsT[d * 130 + sl] = f2bf(acc[m][n][r]);
                    }
                }
            __syncthreads();
            const int d = t >> 2, sc = (t & 3) * 32;
            unsigned short* dst = VT + ((size_t)kvh * HD + d) * S_LEN + m0 + sc;
            const unsigned short* srcl = &ldsT[d * 130 + sc];
#pragma unroll
            for (int j = 0; j < 16; j++)
                ((uint32_t*)dst)[j] = *(const uint32_t*)&srcl[2 * j];
        }
    }
}

// ---------------- flash attention v10 (R17 version, unchanged) -------------
__global__ __launch_bounds__(256) void flash_kernel(
    const unsigned short* __restrict__ Q, const unsigned short* __restrict__ Kg,
    const unsigned short* __restrict__ VTg, unsigned short* __restrict__ O,
    float* __restrict__ Opart, float* __restrict__ ML) {
    __shared__ unsigned short Ks[3][2048];
    __shared__ unsigned short Vs[3][2048];
    const int t = threadIdx.x, lane = t & 63, wave = t >> 6;
    const int l31 = lane & 31, hi = lane >> 5;
    const int bid = blockIdx.x;
    const int h = bid & 31, u = bid >> 5;  // u 0..23
    const int qt = kUQT[u], ch = kUCH[u], sp = kUSP[u];
    const int kvh = h >> 2;

    const int kt0 = sp ? ch * (2 * qt + 2) : 0;
    const int ktN = kt0 + (sp ? (2 * qt + 2) : (4 * qt + 4));

    const int srow = t >> 3;
    const int scol = ((t & 7) * 8) ^ ((srow & 7) * 8);
    const unsigned short* gk = Kg + ((size_t)kvh * S_LEN + srow) * HD + scol;
    const int vrow = t >> 2;
    const int vcol = (((t & 3) ^ (vrow & 3)) * 8);
    const unsigned short* gv = VTg + ((size_t)kvh * HD + vrow) * S_LEN + vcol;

    const int q0 = qt * 128;
    const int qw0 = q0 + wave * 32;  // wave's first q row
    const int q = qw0 + l31;         // THIS lane's q row

    const unsigned short* qp = Q + ((size_t)h * S_LEN + q) * HD + hi * 8;
    bf16x8 qf0 = *(const bf16x8*)(qp);
    bf16x8 qf1 = *(const bf16x8*)(qp + 16);
    bf16x8 qf2 = *(const bf16x8*)(qp + 32);
    bf16x8 qf3 = *(const bf16x8*)(qp + 48);

    f32x16 oacc0 = {}, oacc1 = {};  // O^T: col q, rows d (0..31 / 32..63)
    float mrun = -1e30f, lrun = 0.f;

#define FSTAGE(buf, kt)                                                       \
    {                                                                         \
        const size_t kv_ = (size_t)(kt) * 32;                                 \
        GLDS16(gk + kv_ * HD, &Ks[buf][t * 8]);                               \
        GLDS16(gv + kv_, &Vs[buf][t * 8]);                                    \
    }

    FSTAGE(0, kt0);
    FSTAGE(1, kt0 + 1);

    int cb = 0, pfb = 2;
#pragma unroll 1
    for (int kt = kt0; kt < ktN; ++kt) {
        if (kt + 1 < ktN) asm volatile("s_waitcnt vmcnt(2)" ::: "memory");
        else              asm volatile("s_waitcnt vmcnt(0)" ::: "memory");
        __builtin_amdgcn_s_barrier();
        __builtin_amdgcn_sched_barrier(0);
        if (kt + 2 < ktN) FSTAGE(pfb, kt + 2);
        pfb = (pfb == 2) ? 0 : pfb + 1;
        const int kv0 = kt * 32;
        const int mycb = cb;
        cb = (cb == 2) ? 0 : cb + 1;
        if (kv0 > qw0 + 31) continue;  // fully-masked for this wave
        const unsigned short* ksb = Ks[mycb];
        const unsigned short* vsb = Vs[mycb];
        const int sw = (l31 & 7) * 8;
        // S^T = K Q^T (32 kv x 32 q)
        f32x16 s0 = {};
#pragma unroll
        for (int kc = 0; kc < 4; kc++) {
            bf16x8 k0 = *(const bf16x8*)&ksb[l31 * 64 + ((16 * kc + 8 * hi) ^ sw)];
            bf16x8 qc = (kc == 0) ? qf0 : (kc == 1) ? qf1 : (kc == 2) ? qf2 : qf3;
            s0 = __builtin_amdgcn_mfma_f32_32x32x16_bf16(k0, qc, s0, 0, 0, 0);
        }
        float p0[16];
        if (kv0 + 31 <= qw0) {  // interior tile
#pragma unroll
            for (int r = 0; r < 16; r++) p0[r] = s0[r];
        } else {
#pragma unroll
            for (int r = 0; r < 16; r++) {
                int rr = (r & 3) + 8 * (r >> 2) + 4 * hi;
                p0[r] = (kv0 + rr <= q) ? s0[r] : -1e30f;
            }
        }
        float t8[8];
#pragma unroll
        for (int r = 0; r < 8; r++) t8[r] = fmaxf(p0[r], p0[r + 8]);
        float lm = fmaxf(fmaxf(fmaxf(t8[0], t8[4]), fmaxf(t8[1], t8[5])),
                         fmaxf(fmaxf(t8[2], t8[6]), fmaxf(t8[3], t8[7])));
        if (!__all(lm - mrun <= 8.f)) {
            float rm = fmaxf(lm, __shfl_xor(lm, 32));
            float mnew = fmaxf(mrun, rm);
            float sc = exp2f(mrun - mnew);
            mrun = mnew;
            lrun *= sc;
            oacc0 *= sc;
            oacc1 *= sc;
        }
#pragma unroll
        for (int r = 0; r < 16; r++) p0[r] = exp2f(p0[r] - mrun);
        float sA = 0.f, sB = 0.f;
#pragma unroll
        for (int r = 0; r < 4; r++) {
            sA += p0[r] + p0[r + 4];
            sB += p0[r + 8] + p0[r + 12];
        }
        lrun += sA + sB;
        bf16x8 pf[2];
#pragma unroll
        for (int kc = 0; kc < 2; kc++) {
            const int sub = kc * 8;
            uint32_t Wl0 = cvt_pk_bf16(p0[sub + 0], p0[sub + 1]);
            uint32_t Wl1 = cvt_pk_bf16(p0[sub + 2], p0[sub + 3]);
            uint32_t Wh0 = cvt_pk_bf16(p0[sub + 4], p0[sub + 5]);
            uint32_t Wh1 = cvt_pk_bf16(p0[sub + 6], p0[sub + 7]);
            uint32_t sw0 = hi ? Wl0 : Wh0, sw1 = hi ? Wl1 : Wh1;  // sent
            uint32_t rc0 = __shfl_xor((int)sw0, 32);
            uint32_t rc1 = __shfl_xor((int)sw1, 32);
            uint32_t kp0 = hi ? Wh0 : Wl0, kp1 = hi ? Wh1 : Wl1;  // kept
            uint32_t F0 = hi ? rc0 : kp0;
            uint32_t F1 = hi ? rc1 : kp1;
            uint32_t F2 = hi ? kp0 : rc0;
            uint32_t F3 = hi ? kp1 : rc1;
            uint4 fu = {F0, F1, F2, F3};
            pf[kc] = *(const bf16x8*)&fu;
        }
#pragma unroll
        for (int kc = 0; kc < 2; kc++) {
            const int vs0 = ((kc * 2 + hi) ^ (l31 & 3)) * 8;
            bf16x8 v0 = *(const bf16x8*)&vsb[l31 * 32 + vs0];
            bf16x8 v1 = *(const bf16x8*)&vsb[(32 + l31) * 32 + vs0];
            oacc0 = __builtin_amdgcn_mfma_f32_32x32x16_bf16(v0, pf[kc], oacc0, 0, 0, 0);
            oacc1 = __builtin_amdgcn_mfma_f32_32x32x16_bf16(v1, pf[kc], oacc1, 0, 0, 0);
        }
    }
#undef FSTAGE
    lrun += __shfl_xor(lrun, 32);
    const int qrow = wave * 32 + l31;
    if (sp) {
        const int pidx = (h * 8 + (qt - 8)) * 2 + ch;
        float* po = Opart + ((size_t)pidx * 128 + qrow) * 64 + 4 * hi;
#pragma unroll
        for (int g = 0; g < 4; g++) {
            float4 a = {oacc0[4 * g], oacc0[4 * g + 1], oacc0[4 * g + 2], oacc0[4 * g + 3]};
            *(float4*)(po + 8 * g) = a;
            float4 b = {oacc1[4 * g], oacc1[4 * g + 1], oacc1[4 * g + 2], oacc1[4 * g + 3]};
            *(float4*)(po + 32 + 8 * g) = b;
        }
        if (hi == 0) {
            ML[((size_t)pidx * 128 + qrow) * 2] = mrun;
            ML[((size_t)pidx * 128 + qrow) * 2 + 1] = lrun;
        }
    } else {
        float rinv = 1.f / lrun;
        unsigned short* ob = O + ((size_t)h * S_LEN + q) * HD + 4 * hi;
#pragma unroll
        for (int g = 0; g < 4; g++) {
            uint32_t a0 = cvt_pk_bf16(oacc0[4 * g] * rinv, oacc0[4 * g + 1] * rinv);
            uint32_t a1 = cvt_pk_bf16(oacc0[4 * g + 2] * rinv, oacc0[4 * g + 3] * rinv);
            uint2 u0 = {a0, a1};
            *(uint2*)(ob + 8 * g) = u0;
            uint32_t b0 = cvt_pk_bf16(oacc1[4 * g] * rinv, oacc1[4 * g + 1] * rinv);
            uint32_t b1 = cvt_pk_bf16(oacc1[4 * g + 2] * rinv, oacc1[4 * g + 3] * rinv);
            uint2 u1 = {b0, b1};
            *(uint2*)(ob + 32 + 8 * g) = u1;
        }
    }
}

// ---- per-head fw GEMM + SiLU, with fused 2-way partial combine ------------
// Rows s<1024 read bf16 attn; rows s>=1024 merge the two kv-chunk fp32
// partials inline (replaces flash_combine kernel).
__global__ __launch_bounds__(256) void fw_silu_kernel(
    const unsigned short* __restrict__ AT, const unsigned short* __restrict__ fwT,
    const float* __restrict__ fb, const float* __restrict__ Opart,
    const float* __restrict__ ML, unsigned short* __restrict__ h2) {
    const int t = threadIdx.x, lane = t & 63, wave = t >> 6;
    const int l15 = lane & 15, lhi = lane >> 4;
    const int r0 = blockIdx.x * 64 + wave * 16;
    const int row = r0 + l15;
    const int hh = row >> 11, s = row & (S_LEN - 1);
    bf16x8 a0, a1;
    if (s < 1024) {
        const unsigned short* ap = AT + (size_t)row * HD + lhi * 8;
        a0 = *(const bf16x8*)ap;
        a1 = *(const bf16x8*)(ap + 32);
    } else {
        const int qt = s >> 7, qrow = s & 127;
        const int pidx = (hh * 8 + (qt - 8)) * 2;
        const float* mlp = ML + ((size_t)pidx * 128 + qrow) * 2;
        const float* mlq = ML + ((size_t)(pidx + 1) * 128 + qrow) * 2;
        float mA = mlp[0], lA = mlp[1], mB = mlq[0], lB = mlq[1];
        float mm = fmaxf(mA, mB);
        float wA = exp2f(mA - mm), wB = exp2f(mB - mm);
        float rv = 1.f / (lA * wA + lB * wB);
        const float* pA = Opart + ((size_t)pidx * 128 + qrow) * 64;
        const float* pB = pA + 8192;
#pragma unroll
        for (int half = 0; half < 2; half++) {
            int db = half * 32 + lhi * 8;
            float4 x0 = *(const float4*)&pA[db], x1 = *(const float4*)&pA[db + 4];
            float4 y0 = *(const float4*)&pB[db], y1 = *(const float4*)&pB[db + 4];
            uint32_t w0 = cvt_pk_bf16((x0.x * wA + y0.x * wB) * rv, (x0.y * wA + y0.y * wB) * rv);
            uint32_t w1 = cvt_pk_bf16((x0.z * wA + y0.z * wB) * rv, (x0.w * wA + y0.w * wB) * rv);
            uint32_t w2 = cvt_pk_bf16((x1.x * wA + y1.x * wB) * rv, (x1.y * wA + y1.y * wB) * rv);
            uint32_t w3 = cvt_pk_bf16((x1.z * wA + y1.z * wB) * rv, (x1.w * wA + y1.w * wB) * rv);
            uint4 u = {w0, w1, w2, w3};
            if (half == 0) a0 = *(const bf16x8*)&u;
            else           a1 = *(const bf16x8*)&u;
        }
    }
    f32x4 acc[4] = {};
#pragma unroll
    for (int nb = 0; nb < 4; nb++) {
        const unsigned short* bp = fwT + (size_t)(nb * 16 + l15) * HD + lhi * 8;
        bf16x8 b0 = *(const bf16x8*)bp;
        bf16x8 b1 = *(const bf16x8*)(bp + 32);
        acc[nb] = __builtin_amdgcn_mfma_f32_16x16x32_bf16(a0, b0, acc[nb], 0, 0, 0);
        acc[nb] = __builtin_amdgcn_mfma_f32_16x16x32_bf16(a1, b1, acc[nb], 0, 0, 0);
    }
#pragma unroll
    for (int nb = 0; nb < 4; nb++) {
        int col = nb * 16 + l15;
        float bias = fb[col];
#pragma unroll
        for (int r = 0; r < 4; r++) {
            int orow = r0 + lhi * 4 + r;  // h*S + s
            int os = orow & (S_LEN - 1), oh = orow >> 11;
            float xv = acc[nb][r] + bias;
            float sg = 1.f / (1.f + exp2f(-xv * 1.44269504f));
            h2[(size_t)os * DMODEL + oh * HD + col] = f2bf(xv * sg);
        }
    }
}

extern "C" void kernel_launch(void* const* d_in, const int* in_sizes, int n_in,
                              void* d_out, int out_size, void* d_ws, size_t ws_size,
                              hipStream_t stream) {
    const float* x = (const float*)d_in[0];
    const float* fcos = (const float*)d_in[1];
    const float* fsin = (const float*)d_in[2];
    const float* wq = (const float*)d_in[4];
    const float* wk = (const float*)d_in[5];
    const float* wv = (const float*)d_in[6];
    const float* wo = (const float*)d_in[7];
    const float* fw = (const float*)d_in[8];
    const float* fb = (const float*)d_in[9];
    float* out = (float*)d_out;

    char* ws = (char*)d_ws;
    size_t off = 0;
    auto alloc = [&](size_t bytes) {
        void* p = ws + off;
        off += (bytes + 255) & ~(size_t)255;
        return p;
    };
    unsigned short* wqkvT = (unsigned short*)alloc((size_t)3072 * 2048 * 2);
    unsigned short* woT   = (unsigned short*)alloc((size_t)2048 * 2048 * 2);
    unsigned short* fwT   = (unsigned short*)alloc((size_t)64 * 64 * 2);
    unsigned short* Qb    = (unsigned short*)alloc((size_t)NH * S_LEN * HD * 2);
    unsigned short* Kb    = (unsigned short*)alloc((size_t)NKV * S_LEN * HD * 2);
    unsigned short* VT    = (unsigned short*)alloc((size_t)NKV * HD * S_LEN * 2);
    unsigned short* xb    = (unsigned short*)alloc((size_t)2048 * 2048 * 2);
    float*          ML    = (float*)alloc((size_t)512 * 128 * 2 * 4);
    unsigned short* attn  = (unsigned short*)alloc((size_t)NH * S_LEN * HD * 2);
    float*          Opart = (float*)alloc((size_t)512 * 128 * 64 * 4);
    unsigned short* h2 = xb;  // reuses xb (x dead after QKV gemm)

    prep_kernel<<<dim3(64, 64, 6), dim3(32, 8), 0, stream>>>(
        wq, wk, wv, wo, fw, x, wqkvT, woT, fwT, xb);

    // QKV GEMM (128x64, BK=32) w/ fused RoPE/V-transpose epilogue
    gemm_bt_kernel<1><<<dim3(16, 48), 256, 0, stream>>>(
        xb, wqkvT, nullptr, Qb, Kb, VT, fcos, fsin, 2048, 3072, 2048);

    flash_kernel<<<768, 256, 0, stream>>>(Qb, Kb, VT, attn, Opart, ML);

    // fw GEMM + SiLU with fused partial-combine (flash_combine deleted)
    fw_silu_kernel<<<1024, 256, 0, stream>>>(attn, fwT, fb, Opart, ML, h2);

    // wo GEMM: 128x64, BK=32, fp32 out
    gemm_bt_kernel<0><<<dim3(16, 32), 256, 0, stream>>>(
        h2, woT, out, nullptr, nullptr, nullptr, nullptr, nullptr,
        2048, 2048, 2048);
}